// Round 1
// 17739.619 us; speedup vs baseline: 1.1446x; 1.1446x over previous
//
#include <hip/hip_runtime.h>
#include <cstdint>
#include <cstddef>

// Problem dims: B=32, T=2048, D=512, H=512, 4H=2048
#define TT 2048
#define DD 512

// ---------------------------------------------------------------------------
// Phase 1 (chunked): xp = inputs @ Wi + b, written in SCAN-NATIVE layout:
//   xp[tl][gate 4][g 4][gb 128][b 8][jl 4]   (T_CH*65536 floats per chunk)
// fp32 vector GEMM, 128x128x16 tiles, 8x8 per thread.  (unchanged)
// ---------------------------------------------------------------------------
#define BM 128
#define BN 128
#define BK 16

__global__ __launch_bounds__(256) void xproj_gemm(
    const float* __restrict__ A,    // [32*2048, 512]
    const float* __restrict__ W,    // [512, 2048]
    const float* __restrict__ bias, // [2048]
    float* __restrict__ C,          // xp chunk, scan layout
    int t0, int tmask, int tlog)    // T_CH = tmask+1 = 1<<tlog
{
    __shared__ __align__(16) float As[BK][BM + 4];   // [k][m], transposed on load
    __shared__ __align__(16) float Bs[BK][BN + 4];   // [k][n]
    const int tid = threadIdx.x;
    const int nt = blockIdx.x;
    const int mt = blockIdx.y;
    const int m_base = mt * BM;        // chunk-local row base (m = bglob*T_CH + tl)
    const int n_base = nt * BN;
    const int ty = tid >> 4;
    const int tx = tid & 15;

    float acc[8][8];
#pragma unroll
    for (int i = 0; i < 8; ++i)
#pragma unroll
        for (int j = 0; j < 8; ++j) acc[i][j] = 0.f;

    for (int k0 = 0; k0 < DD; k0 += BK) {
#pragma unroll
        for (int j = 0; j < 2; ++j) {
            int idx = tid * 2 + j;             // 0..511
            int rowl = idx >> 2, q = idx & 3;  // A: 128 rows x 4 float4
            int rc = m_base + rowl;            // chunk-local row
            int rg = ((rc >> tlog) << 11) + t0 + (rc & tmask);  // global input row
            float4 av = *(const float4*)(A + (size_t)rg * DD + k0 + q * 4);
            As[q * 4 + 0][rowl] = av.x;
            As[q * 4 + 1][rowl] = av.y;
            As[q * 4 + 2][rowl] = av.z;
            As[q * 4 + 3][rowl] = av.w;
            int kr = idx >> 5, nq = idx & 31;  // B: 16 rows x 32 float4
            *(float4*)&Bs[kr][nq * 4] =
                *(const float4*)(W + (size_t)(k0 + kr) * 2048 + n_base + nq * 4);
        }
        __syncthreads();
#pragma unroll
        for (int kk = 0; kk < BK; ++kk) {
            float a[8], bb[8];
            *(float4*)&a[0]  = *(const float4*)&As[kk][ty * 8];
            *(float4*)&a[4]  = *(const float4*)&As[kk][ty * 8 + 4];
            *(float4*)&bb[0] = *(const float4*)&Bs[kk][tx * 8];
            *(float4*)&bb[4] = *(const float4*)&Bs[kk][tx * 8 + 4];
#pragma unroll
            for (int i = 0; i < 8; ++i)
#pragma unroll
                for (int j = 0; j < 8; ++j)
                    acc[i][j] = fmaf(a[i], bb[j], acc[i][j]);
        }
        __syncthreads();
    }
#pragma unroll
    for (int i = 0; i < 8; ++i) {
        int m = m_base + ty * 8 + i;
        int bglob = m >> tlog, tl = m & tmask;
        int g = bglob >> 3, b = bglob & 7;
#pragma unroll
        for (int j = 0; j < 8; j += 4) {
            int n = n_base + tx * 8 + j;       // n % 4 == 0 -> jl = 0
            int gate = n >> 9, gb = (n & 511) >> 2;
            float4 v;
            v.x = acc[i][j + 0] + bias[n + 0];
            v.y = acc[i][j + 1] + bias[n + 1];
            v.z = acc[i][j + 2] + bias[n + 2];
            v.w = acc[i][j + 3] + bias[n + 3];
            size_t addr = (((((size_t)tl * 4 + gate) * 4 + g) * 128 + gb) * 8 + b) * 4;
            *(float4*)(C + addr) = v;
        }
    }
}

// ---------------------------------------------------------------------------
// Phase 2: persistent LSTM scan over one T-chunk.
// 4 groups x 128 blocks. Group g owns batches [8g, 8g+8).
// Block gb owns h-cols [4gb, 4gb+4) -> 16 z-cols.
//
// NEW this round:
//  * Wh slice held in REGISTERS (wave = col-group of 4 cols, lane = k-chunk
//    {4l..4l+3} U {256+4l..256+4l+3}): the dot loop issues 16 conflict-free
//    ds_read_b128 of h per thread per step instead of 128 (8x LDS cut;
//    weights were being re-read from LDS every one of 2048 steps).
//  * k-partials reduced across the 64 lanes with a value-halving shfl_xor
//    butterfly (lane ends holding output idx = bitrev5(lane&31)).
//  * Single-leg barrier: every block stores its flag; ALL blocks poll all
//    128 group flags (tid<128) -> one MALL round-trip instead of two
//    (flags->master + gen->everyone).
// ---------------------------------------------------------------------------
#define NGRP 4
#define BPG  128
#define WHP  516   // padded row stride (floats)
#define HP   516
#define FS   32    // flag padding stride in u32 (128 B)

__device__ __forceinline__ void flag_barrier(unsigned* gflags, int tid, int gb,
                                             unsigned e) {
    // __syncthreads lowers to s_waitcnt vmcnt(0) lgkmcnt(0); s_barrier
    // -> every thread's agent-scope stores are at the coherence point
    // before the flag store issues.
    __syncthreads();
    if (tid == 0)
        __hip_atomic_store(gflags + gb * FS, e, __ATOMIC_RELAXED, __HIP_MEMORY_SCOPE_AGENT);
    if (tid < BPG) {
        unsigned* f = gflags + tid * FS;
        while (__hip_atomic_load(f, __ATOMIC_RELAXED, __HIP_MEMORY_SCOPE_AGENT) < e)
            __builtin_amdgcn_s_sleep(1);
    }
    __syncthreads();
}

// butterfly reduce step: halve the live value count across lanes differing in bit D
template<int D, int HALF>
__device__ __forceinline__ void rstep(float* p, int lane) {
    const bool hi = (lane & D) != 0;
#pragma unroll
    for (int i = 0; i < HALF; ++i) {
        float send = hi ? p[i] : p[i + HALF];
        float recv = __shfl_xor(send, D, 64);
        p[i] = (hi ? p[i + HALF] : p[i]) + recv;
    }
}

__global__ __launch_bounds__(256) void lstm_scan(
    const float* __restrict__ xp,   // chunk, scan layout (see xproj_gemm)
    const float* __restrict__ Wh,   // [512, 2048]
    const float* __restrict__ c0,   // [32, 512]
    const float* __restrict__ h0,   // [32, 512]
    float* __restrict__ out,        // [32, 2048, 512]
    float* hbuf,                    // [2][32][512] ping-pong (persists)
    float* __restrict__ cbuf,       // [32][512] c-state (persists)
    unsigned* __restrict__ flags,   // [4][128][FS]
    int t0, int T_CH, unsigned ep0)
{
    __shared__ __align__(16) float wh_lds[16 * WHP];  // 16 cols x 512 (padded) 33,024 B
    __shared__ __align__(16) float h_lds[8 * HP];     // 8 batches x 512        16,512 B
    __shared__ float zsum[128];                       // [wave(gate)][c*8+b]
    __shared__ float xs[8 * 16];

    const int tid = threadIdx.x;
    const int blk = blockIdx.x;
    const int g   = blk >> 7;     // group 0..3
    const int gb  = blk & 127;
    const int j0  = gb * 4;       // owned h-col base

    unsigned* gflags = flags + (size_t)g * BPG * FS;

    // ---- stage Wh slice into LDS (once; source for the register hoist) ----
#pragma unroll
    for (int it = 0; it < 8; ++it) {
        int idx = tid + it * 256;          // (k, gate)
        int gate = idx & 3, k = idx >> 2;
        float4 v = *(const float4*)(Wh + (size_t)k * 2048 + gate * 512 + j0);
        wh_lds[(gate * 4 + 0) * WHP + k] = v.x;
        wh_lds[(gate * 4 + 1) * WHP + k] = v.y;
        wh_lds[(gate * 4 + 2) * WHP + k] = v.z;
        wh_lds[(gate * 4 + 3) * WHP + k] = v.w;
    }

    const int lane = tid & 63;
    const int wv   = tid >> 6;    // wave = col-group = gate

    // gate-role (tid < 32): b = tid>>2, j = tid&3
    float creg = 0.f;
    if (tid < 32) {
        int b = tid >> 2, j = tid & 3;
        size_t o = (size_t)(8 * g + b) * 512 + j0 + j;
        if (t0 == 0) {
            creg = c0[o];
            __hip_atomic_store(hbuf + o, h0[o], __ATOMIC_RELAXED, __HIP_MEMORY_SCOPE_AGENT);
        } else {
            creg = cbuf[o];    // h already in hbuf[(t0&1)] from prev chunk
        }
    }
    unsigned ep = ep0;
    flag_barrier(gflags, tid, gb, ++ep);

    // ---- hoist this thread's Wh fragment into registers (never re-read) ----
    // thread owns cols cc = wv*4+c (c=0..3), k in {4*lane..+3} U {256+4*lane..+3}
    float4 wa[4], wb[4];
#pragma unroll
    for (int c = 0; c < 4; ++c) {
        const float* wp = wh_lds + (wv * 4 + c) * WHP + lane * 4;
        wa[c] = *(const float4*)wp;
        wb[c] = *(const float4*)(wp + 256);
    }
    const float* hp = h_lds + lane * 4;

    for (int tl = 0; tl < T_CH; ++tl) {
        const int t = t0 + tl;
        const int cur = t & 1;

        // issue xp load early (dense 512B/block/step, plain cached loads)
        float4 xv4;
        if (tid < 32) {
            int gate = tid >> 3, b = tid & 7;
            xv4 = *(const float4*)(xp +
                  ((((size_t)tl * 4 + gate) * 4 + g) * 128 + gb) * 32 + b * 4);
        }

        // stage group h (8 x 512) into LDS via coherence-point loads
        {
            const float* hsrc = hbuf + (size_t)cur * (32 * 512) + (size_t)(8 * g) * 512;
#pragma unroll
            for (int i = 0; i < 16; ++i) {
                int p_ = tid + i * 256;
                float v = __hip_atomic_load(hsrc + p_, __ATOMIC_RELAXED, __HIP_MEMORY_SCOPE_AGENT);
                h_lds[(p_ >> 9) * HP + (p_ & 511)] = v;
            }
        }
        __syncthreads();

        // dot: p[c*8+b] = sum over this lane's 8 k of h[b][k]*Wh[k][cc]
        // h reads: 2 b128/batch at stride 16B across lanes -> 8 dwords/bank,
        // exactly the b128 baseline -> conflict-free.
        float p[32];
#pragma unroll
        for (int i = 0; i < 32; ++i) p[i] = 0.f;
#pragma unroll
        for (int b = 0; b < 8; ++b) {
            float4 ha = *(const float4*)(hp + b * HP);
            float4 hb = *(const float4*)(hp + b * HP + 256);
#pragma unroll
            for (int c = 0; c < 4; ++c) {
                p[c * 8 + b] = fmaf(ha.x, wa[c].x, p[c * 8 + b]);
                p[c * 8 + b] = fmaf(ha.y, wa[c].y, p[c * 8 + b]);
                p[c * 8 + b] = fmaf(ha.z, wa[c].z, p[c * 8 + b]);
                p[c * 8 + b] = fmaf(ha.w, wa[c].w, p[c * 8 + b]);
                p[c * 8 + b] = fmaf(hb.x, wb[c].x, p[c * 8 + b]);
                p[c * 8 + b] = fmaf(hb.y, wb[c].y, p[c * 8 + b]);
                p[c * 8 + b] = fmaf(hb.z, wb[c].z, p[c * 8 + b]);
                p[c * 8 + b] = fmaf(hb.w, wb[c].w, p[c * 8 + b]);
            }
        }
        // reduce the 32 partials across 64 k-lanes (value-halving butterfly)
        rstep<1, 16>(p, lane);
        rstep<2, 8>(p, lane);
        rstep<4, 4>(p, lane);
        rstep<8, 2>(p, lane);
        rstep<16, 1>(p, lane);
        p[0] += __shfl_xor(p[0], 32, 64);
        // lane ends holding output idx = bitrev5(lane&31): c = idx>>3, b = idx&7
        if (lane < 32) {
            int idx = ((lane & 1) << 4) | ((lane & 2) << 2) | (lane & 4)
                    | ((lane >> 2) & 2) | ((lane >> 4) & 1);
            zsum[wv * 32 + idx] = p[0];
        }
        if (tid < 32) {
            int gate = tid >> 3, b = tid & 7;
            *(float4*)&xs[(b * 4 + gate) * 4] = xv4;
        }
        __syncthreads();

        // gates: flax order i, f, g, o
        if (tid < 32) {
            int b = tid >> 2, j = tid & 3;
            float z[4];
#pragma unroll
            for (int gate = 0; gate < 4; ++gate)
                z[gate] = xs[(b * 4 + gate) * 4 + j] + zsum[gate * 32 + j * 8 + b];
            float si = 1.f / (1.f + expf(-z[0]));
            float sf = 1.f / (1.f + expf(-z[1]));
            float tg = tanhf(z[2]);
            float so = 1.f / (1.f + expf(-z[3]));
            float cn = sf * creg + si * tg;
            float hn = so * tanhf(cn);
            creg = cn;
            __hip_atomic_store(
                hbuf + (size_t)(cur ^ 1) * (32 * 512) + (size_t)(8 * g + b) * 512 + j0 + j,
                hn, __ATOMIC_RELAXED, __HIP_MEMORY_SCOPE_AGENT);
            out[((size_t)(8 * g + b) * TT + t) * 512 + j0 + j] = hn;
        }
        flag_barrier(gflags, tid, gb, ++ep);
    }

    // persist c for next chunk launch (plain; kernel-boundary coherence)
    if (tid < 32) {
        int b = tid >> 2, j = tid & 3;
        cbuf[(size_t)(8 * g + b) * 512 + j0 + j] = creg;
    }
}

// ---------------------------------------------------------------------------
extern "C" void kernel_launch(void* const* d_in, const int* in_sizes, int n_in,
                              void* d_out, int out_size, void* d_ws, size_t ws_size,
                              hipStream_t stream) {
    const float* inputs = (const float*)d_in[0];
    // d_in[1] = input_paddings: unused (reference discards it)
    const float* c0   = (const float*)d_in[2];
    const float* h0   = (const float*)d_in[3];
    const float* Wi   = (const float*)d_in[4];
    const float* Wh   = (const float*)d_in[5];
    const float* bias = (const float*)d_in[6];
    float* out = (float*)d_out;

    // ws layout (floats): [hbuf 32768][cbuf 16384][flags 16384 u32][gen 128 u32][xp]
    float* ws_f = (float*)d_ws;
    float* hbuf = ws_f;
    float* cbuf = ws_f + 32768;
    unsigned* flags = (unsigned*)(ws_f + 49152);
    float* xp = ws_f + 49152 + 16384 + 128;          // 65664 (16B aligned)
    const size_t extras_bytes = 65664 * sizeof(float);

    // pick largest T-chunk (pow2, <=256) whose xp slab fits in ws
    int T_CH = 256;
    while (T_CH > 32 &&
           extras_bytes + (size_t)T_CH * 65536 * sizeof(float) > ws_size)
        T_CH >>= 1;
    int tlog = 31 - __builtin_clz((unsigned)T_CH);

    // flags are 0xAA-poisoned before every call; epochs are monotone from 1
    hipMemsetAsync(flags, 0, (NGRP * BPG * FS + NGRP * FS) * sizeof(unsigned), stream);

    for (int t0 = 0; t0 < TT; t0 += T_CH) {
        dim3 g1(2048 / BN, (32 * T_CH) / BM);
        xproj_gemm<<<g1, 256, 0, stream>>>(inputs, Wi, bias, xp, t0, T_CH - 1, tlog);

        const float* xp_c = xp;
        int t0_arg = t0, tch_arg = T_CH;
        unsigned ep0 = (unsigned)(t0 / T_CH) * (unsigned)(T_CH + 1);
        void* args[] = { (void*)&xp_c, (void*)&Wh, (void*)&c0, (void*)&h0,
                         (void*)&out, (void*)&hbuf, (void*)&cbuf,
                         (void*)&flags,
                         (void*)&t0_arg, (void*)&tch_arg, (void*)&ep0 };
        hipLaunchCooperativeKernel((const void*)lstm_scan, dim3(NGRP * BPG), dim3(256),
                                   args, 0, stream);
    }
}

// Round 2
// 9200.031 us; speedup vs baseline: 2.2070x; 1.9282x over previous
//
#include <hip/hip_runtime.h>
#include <cstdint>
#include <cstddef>

// Problem dims: B=32, T=2048, D=512, H=512, 4H=2048
#define TT 2048
#define DD 512

// ---------------------------------------------------------------------------
// Phase 1 (chunked): xp = inputs @ Wi + b, written in SCAN-NATIVE layout:
//   xp[tl][gate 4][g 4][gb 128][b 8][jl 4]   (T_CH*65536 floats per chunk)
// fp32 vector GEMM, 128x128x16 tiles, 8x8 per thread.  (unchanged)
// ---------------------------------------------------------------------------
#define BM 128
#define BN 128
#define BK 16

__global__ __launch_bounds__(256) void xproj_gemm(
    const float* __restrict__ A,    // [32*2048, 512]
    const float* __restrict__ W,    // [512, 2048]
    const float* __restrict__ bias, // [2048]
    float* __restrict__ C,          // xp chunk, scan layout
    int t0, int tmask, int tlog)    // T_CH = tmask+1 = 1<<tlog
{
    __shared__ __align__(16) float As[BK][BM + 4];   // [k][m], transposed on load
    __shared__ __align__(16) float Bs[BK][BN + 4];   // [k][n]
    const int tid = threadIdx.x;
    const int nt = blockIdx.x;
    const int mt = blockIdx.y;
    const int m_base = mt * BM;        // chunk-local row base (m = bglob*T_CH + tl)
    const int n_base = nt * BN;
    const int ty = tid >> 4;
    const int tx = tid & 15;

    float acc[8][8];
#pragma unroll
    for (int i = 0; i < 8; ++i)
#pragma unroll
        for (int j = 0; j < 8; ++j) acc[i][j] = 0.f;

    for (int k0 = 0; k0 < DD; k0 += BK) {
#pragma unroll
        for (int j = 0; j < 2; ++j) {
            int idx = tid * 2 + j;             // 0..511
            int rowl = idx >> 2, q = idx & 3;  // A: 128 rows x 4 float4
            int rc = m_base + rowl;            // chunk-local row
            int rg = ((rc >> tlog) << 11) + t0 + (rc & tmask);  // global input row
            float4 av = *(const float4*)(A + (size_t)rg * DD + k0 + q * 4);
            As[q * 4 + 0][rowl] = av.x;
            As[q * 4 + 1][rowl] = av.y;
            As[q * 4 + 2][rowl] = av.z;
            As[q * 4 + 3][rowl] = av.w;
            int kr = idx >> 5, nq = idx & 31;  // B: 16 rows x 32 float4
            *(float4*)&Bs[kr][nq * 4] =
                *(const float4*)(W + (size_t)(k0 + kr) * 2048 + n_base + nq * 4);
        }
        __syncthreads();
#pragma unroll
        for (int kk = 0; kk < BK; ++kk) {
            float a[8], bb[8];
            *(float4*)&a[0]  = *(const float4*)&As[kk][ty * 8];
            *(float4*)&a[4]  = *(const float4*)&As[kk][ty * 8 + 4];
            *(float4*)&bb[0] = *(const float4*)&Bs[kk][tx * 8];
            *(float4*)&bb[4] = *(const float4*)&Bs[kk][tx * 8 + 4];
#pragma unroll
            for (int i = 0; i < 8; ++i)
#pragma unroll
                for (int j = 0; j < 8; ++j)
                    acc[i][j] = fmaf(a[i], bb[j], acc[i][j]);
        }
        __syncthreads();
    }
#pragma unroll
    for (int i = 0; i < 8; ++i) {
        int m = m_base + ty * 8 + i;
        int bglob = m >> tlog, tl = m & tmask;
        int g = bglob >> 3, b = bglob & 7;
#pragma unroll
        for (int j = 0; j < 8; j += 4) {
            int n = n_base + tx * 8 + j;       // n % 4 == 0 -> jl = 0
            int gate = n >> 9, gb = (n & 511) >> 2;
            float4 v;
            v.x = acc[i][j + 0] + bias[n + 0];
            v.y = acc[i][j + 1] + bias[n + 1];
            v.z = acc[i][j + 2] + bias[n + 2];
            v.w = acc[i][j + 3] + bias[n + 3];
            size_t addr = (((((size_t)tl * 4 + gate) * 4 + g) * 128 + gb) * 8 + b) * 4;
            *(float4*)(C + addr) = v;
        }
    }
}

// ---------------------------------------------------------------------------
// Phase 2: persistent LSTM scan over one T-chunk.
// NEW structure: 4 groups x 64 blocks x 512 threads (1 block/CU, 8 waves).
// Group g owns batches [8g, 8g+8). Block gbb owns h-cols [8*gbb, 8*gbb+8)
// -> 32 z-cols. Wave w (0..7): gate = w&3, col-half ch = w>>2.
// Wh fragment loaded global->registers once (no wh_lds at all).
// Barrier: 64 flags/group; out[] store overlapped with the poll window.
// xp double-buffered in registers. Math bit-identical to previous round.
// ---------------------------------------------------------------------------
#define NGRP 4
#define BPG  64      // blocks per group (was 128)
#define HP   516     // padded h row stride (floats); multiple of 4 for float4
#define FS   32      // flag padding stride in u32 (128 B)
#define GSTRIDE (128 * FS)   // per-group flag slab (layout-compatible with ws)

// butterfly reduce step: halve the live value count across lanes differing in bit D
template<int D, int HALF>
__device__ __forceinline__ void rstep(float* p, int lane) {
    const bool hi = (lane & D) != 0;
#pragma unroll
    for (int i = 0; i < HALF; ++i) {
        float send = hi ? p[i] : p[i + HALF];
        float recv = __shfl_xor(send, D, 64);
        p[i] = (hi ? p[i + HALF] : p[i]) + recv;
    }
}

__global__ __launch_bounds__(512) void lstm_scan(
    const float* __restrict__ xp,   // chunk, scan layout (see xproj_gemm)
    const float* __restrict__ Wh,   // [512, 2048]
    const float* __restrict__ c0,   // [32, 512]
    const float* __restrict__ h0,   // [32, 512]
    float* __restrict__ out,        // [32, 2048, 512]
    float* hbuf,                    // [2][32][512] ping-pong (persists)
    float* __restrict__ cbuf,       // [32][512] c-state (persists)
    unsigned* __restrict__ flags,   // [4][128][FS] (64 used per group)
    int t0, int T_CH, unsigned ep0)
{
    __shared__ __align__(16) float h_lds[8 * HP];   // 8 batches x 512 (padded) 16,512 B
    __shared__ float zsum[256];                     // [wave][c*8+b]
    __shared__ float xs[256];                       // [gate][b][j]
    __shared__ float hn_lds[64];                    // gate lanes' h_new handoff

    const int tid  = threadIdx.x;
    const int blk  = blockIdx.x;
    const int g    = blk >> 6;      // group 0..3
    const int gbb  = blk & 63;
    const int j0   = gbb * 8;       // owned h-col base
    const int lane = tid & 63;
    const int w    = tid >> 6;      // wave 0..7
    const int w_gate = w & 3;
    const int w_ch   = w >> 2;

    unsigned* gflags = flags + (size_t)g * GSTRIDE;

    // ---- Wh fragment: global -> registers, once (cached path, one-time) ----
    // wave covers z-cols (gate=w_gate, hcol=j0+w_ch*4+c), lane covers
    // k in {4*lane..+3} U {256+4*lane..+3}  (identical k-partition to prev round)
    float4 wa[4], wb[4];
    {
        const int colb = w_gate * 512 + j0 + w_ch * 4;
#pragma unroll
        for (int c = 0; c < 4; ++c) {
            const size_t col = colb + c;
            wa[c].x = Wh[(size_t)(4 * lane + 0) * 2048 + col];
            wa[c].y = Wh[(size_t)(4 * lane + 1) * 2048 + col];
            wa[c].z = Wh[(size_t)(4 * lane + 2) * 2048 + col];
            wa[c].w = Wh[(size_t)(4 * lane + 3) * 2048 + col];
            wb[c].x = Wh[(size_t)(256 + 4 * lane + 0) * 2048 + col];
            wb[c].y = Wh[(size_t)(256 + 4 * lane + 1) * 2048 + col];
            wb[c].z = Wh[(size_t)(256 + 4 * lane + 2) * 2048 + col];
            wb[c].w = Wh[(size_t)(256 + 4 * lane + 3) * 2048 + col];
        }
    }

    // xp prefetch geometry (tid < 64): gate = tid>>4, half = (tid>>3)&1, b = tid&7
    const int px_gate = tid >> 4;
    const int px_half = (tid >> 3) & 1;
    const int px_b    = tid & 7;
    const size_t xbase = ((size_t)(px_gate * 4 + g) * 128 + 2 * gbb + px_half) * 32
                       + px_b * 4;

    // gate-role (tid < 64): b = tid>>3, j = tid&7
    float creg = 0.f;
    if (tid < 64) {
        int b = tid >> 3, j = tid & 7;
        size_t o = (size_t)(8 * g + b) * 512 + j0 + j;
        if (t0 == 0) {
            creg = c0[o];
            __hip_atomic_store(hbuf + o, h0[o], __ATOMIC_RELAXED, __HIP_MEMORY_SCOPE_AGENT);
        } else {
            creg = cbuf[o];    // h already in hbuf[(t0&1)] from prev chunk
        }
    }

    // prefetch xp for tl = 0
    float4 xv = make_float4(0.f, 0.f, 0.f, 0.f), xvn;
    if (tid < 64) xv = *(const float4*)(xp + xbase);

    unsigned ep = ep0;
    // ---- init barrier (drains h0 stores) ----
    ++ep;
    __syncthreads();
    if (tid == 0)
        __hip_atomic_store(gflags + gbb * FS, ep, __ATOMIC_RELAXED, __HIP_MEMORY_SCOPE_AGENT);
    if (tid < BPG) {
        unsigned* f = gflags + tid * FS;
        while (__hip_atomic_load(f, __ATOMIC_RELAXED, __HIP_MEMORY_SCOPE_AGENT) < ep)
            __builtin_amdgcn_s_sleep(1);
    }
    __syncthreads();

    const int sb = tid >> 6;      // staging batch = wave index

    for (int tl = 0; tl < T_CH; ++tl) {
        const int t = t0 + tl;
        const int cur = t & 1;

        // ---- stage group h (8 x 512) into LDS via coherence-point loads ----
        {
            const float* hsrc = hbuf + (size_t)cur * (32 * 512) + (size_t)(8 * g) * 512
                              + (size_t)sb * 512;
            float hv[8];
#pragma unroll
            for (int q = 0; q < 8; ++q)
                hv[q] = __hip_atomic_load(hsrc + q * 64 + lane,
                                          __ATOMIC_RELAXED, __HIP_MEMORY_SCOPE_AGENT);
            // prefetch next step's xp while h is in flight
            if (tid < 64 && tl + 1 < T_CH)
                xvn = *(const float4*)(xp + (size_t)(tl + 1) * 65536 + xbase);
            // xs for THIS step from the previously prefetched xv
            if (tid < 64)
                *(float4*)&xs[(px_gate * 8 + px_b) * 8 + px_half * 4] = xv;
#pragma unroll
            for (int q = 0; q < 8; ++q)
                h_lds[sb * HP + q * 64 + lane] = hv[q];
        }
        __syncthreads();

        // ---- dot: p[c*8+b] = sum over this lane's 8 k of h[b][k]*Wh[k][col] ----
        float p[32];
#pragma unroll
        for (int i = 0; i < 32; ++i) p[i] = 0.f;
        const float* hp = h_lds + lane * 4;
#pragma unroll
        for (int b = 0; b < 8; ++b) {
            float4 ha = *(const float4*)(hp + b * HP);
            float4 hb = *(const float4*)(hp + b * HP + 256);
#pragma unroll
            for (int c = 0; c < 4; ++c) {
                p[c * 8 + b] = fmaf(ha.x, wa[c].x, p[c * 8 + b]);
                p[c * 8 + b] = fmaf(ha.y, wa[c].y, p[c * 8 + b]);
                p[c * 8 + b] = fmaf(ha.z, wa[c].z, p[c * 8 + b]);
                p[c * 8 + b] = fmaf(ha.w, wa[c].w, p[c * 8 + b]);
                p[c * 8 + b] = fmaf(hb.x, wb[c].x, p[c * 8 + b]);
                p[c * 8 + b] = fmaf(hb.y, wb[c].y, p[c * 8 + b]);
                p[c * 8 + b] = fmaf(hb.z, wb[c].z, p[c * 8 + b]);
                p[c * 8 + b] = fmaf(hb.w, wb[c].w, p[c * 8 + b]);
            }
        }
        // reduce the 32 partials across 64 k-lanes (value-halving butterfly)
        rstep<1, 16>(p, lane);
        rstep<2, 8>(p, lane);
        rstep<4, 4>(p, lane);
        rstep<8, 2>(p, lane);
        rstep<16, 1>(p, lane);
        p[0] += __shfl_xor(p[0], 32, 64);
        // lane ends holding output idx = bitrev5(lane&31): c = idx>>3, b = idx&7
        if (lane < 32) {
            int idx = ((lane & 1) << 4) | ((lane & 2) << 2) | (lane & 4)
                    | ((lane >> 2) & 2) | ((lane >> 4) & 1);
            zsum[w * 32 + idx] = p[0];
        }
        __syncthreads();

        // ---- gates: flax order i, f, g, o ----
        if (tid < 64) {
            int b = tid >> 3, j = tid & 7;
            float z[4];
#pragma unroll
            for (int gate = 0; gate < 4; ++gate)
                z[gate] = xs[(gate * 8 + b) * 8 + j]
                        + zsum[((j >> 2) * 4 + gate) * 32 + (j & 3) * 8 + b];
            float si = 1.f / (1.f + expf(-z[0]));
            float sf = 1.f / (1.f + expf(-z[1]));
            float tg = tanhf(z[2]);
            float so = 1.f / (1.f + expf(-z[3]));
            float cn = sf * creg + si * tg;
            float hn = so * tanhf(cn);
            creg = cn;
            __hip_atomic_store(
                hbuf + (size_t)(cur ^ 1) * (32 * 512) + (size_t)(8 * g + b) * 512 + j0 + j,
                hn, __ATOMIC_RELAXED, __HIP_MEMORY_SCOPE_AGENT);
            hn_lds[tid] = hn;
            xv = xvn;               // rotate xp double-buffer
        }
        ++ep;
        // ---- barrier: arrive, overlap out-store with poll, depart ----
        __syncthreads();   // drains every thread's stores (h + hn_lds via LDS sync)
        if (tid == 0)
            __hip_atomic_store(gflags + gbb * FS, ep, __ATOMIC_RELAXED, __HIP_MEMORY_SCOPE_AGENT);
        if (tid >= 64 && tid < 128) {
            // out[] store issued during the poll window; its HBM ack is waited
            // a full step later (next stage's vmcnt), never before the flag.
            int t2 = tid - 64, b = t2 >> 3, j = t2 & 7;
            out[((size_t)(8 * g + b) * TT + t) * 512 + j0 + j] = hn_lds[t2];
        }
        if (tid < BPG) {
            unsigned* f = gflags + tid * FS;
            while (__hip_atomic_load(f, __ATOMIC_RELAXED, __HIP_MEMORY_SCOPE_AGENT) < ep)
                __builtin_amdgcn_s_sleep(1);
        }
        __syncthreads();
    }

    // persist c for next chunk launch (plain; kernel-boundary coherence)
    if (tid < 64) {
        int b = tid >> 3, j = tid & 7;
        cbuf[(size_t)(8 * g + b) * 512 + j0 + j] = creg;
    }
}

// ---------------------------------------------------------------------------
extern "C" void kernel_launch(void* const* d_in, const int* in_sizes, int n_in,
                              void* d_out, int out_size, void* d_ws, size_t ws_size,
                              hipStream_t stream) {
    const float* inputs = (const float*)d_in[0];
    // d_in[1] = input_paddings: unused (reference discards it)
    const float* c0   = (const float*)d_in[2];
    const float* h0   = (const float*)d_in[3];
    const float* Wi   = (const float*)d_in[4];
    const float* Wh   = (const float*)d_in[5];
    const float* bias = (const float*)d_in[6];
    float* out = (float*)d_out;

    // ws layout (floats): [hbuf 32768][cbuf 16384][flags 16384 u32][gen 128 u32][xp]
    float* ws_f = (float*)d_ws;
    float* hbuf = ws_f;
    float* cbuf = ws_f + 32768;
    unsigned* flags = (unsigned*)(ws_f + 49152);
    float* xp = ws_f + 49152 + 16384 + 128;          // 65664 (16B aligned)
    const size_t extras_bytes = 65664 * sizeof(float);

    // pick largest T-chunk (pow2, <=256) whose xp slab fits in ws
    int T_CH = 256;
    while (T_CH > 32 &&
           extras_bytes + (size_t)T_CH * 65536 * sizeof(float) > ws_size)
        T_CH >>= 1;
    int tlog = 31 - __builtin_clz((unsigned)T_CH);

    // flags are 0xAA-poisoned before every call; epochs are monotone from 1
    hipMemsetAsync(flags, 0, (NGRP * 128 * FS + NGRP * FS) * sizeof(unsigned), stream);

    for (int t0 = 0; t0 < TT; t0 += T_CH) {
        dim3 g1(2048 / BN, (32 * T_CH) / BM);
        xproj_gemm<<<g1, 256, 0, stream>>>(inputs, Wi, bias, xp, t0, T_CH - 1, tlog);

        const float* xp_c = xp;
        int t0_arg = t0, tch_arg = T_CH;
        unsigned ep0 = (unsigned)(t0 / T_CH) * (unsigned)(T_CH + 1);
        void* args[] = { (void*)&xp_c, (void*)&Wh, (void*)&c0, (void*)&h0,
                         (void*)&out, (void*)&hbuf, (void*)&cbuf,
                         (void*)&flags,
                         (void*)&t0_arg, (void*)&tch_arg, (void*)&ep0 };
        hipLaunchCooperativeKernel((const void*)lstm_scan, dim3(NGRP * BPG), dim3(512),
                                   args, 0, stream);
    }
}